// Round 1
// baseline (187.654 us; speedup 1.0000x reference)
//
#include <hip/hip_runtime.h>
#include <math.h>

// out[i] = sigmoid( X[i,:] . wcomp + c )  where
//   wcomp = W1@W2@W3@W4@W5  (7-vector),  c = ((((b1@W2+b2)@W3+b3)@W4+b4)@W5+b5)
// Pure streaming kernel: 112 MB read + 16 MB write, memory-bound.

__global__ __launch_bounds__(256) void SimpleNN2_kernel(
    const float* __restrict__ X,
    const float* __restrict__ W1, const float* __restrict__ b1,
    const float* __restrict__ W2, const float* __restrict__ b2,
    const float* __restrict__ W3, const float* __restrict__ b3,
    const float* __restrict__ W4, const float* __restrict__ b4,
    const float* __restrict__ W5, const float* __restrict__ b5,
    float* __restrict__ out, int nrows)
{
    __shared__ float sw[8];  // sw[0..6] = composed weight, sw[7] = composed bias

    if (threadIdx.x == 0) {
        // Compose the 7->5->4->3->2->1 chain on one thread (~300 FLOPs, cached reads).
        float A[7][5], B[7][4], C[7][3], D[7][2];
        for (int i = 0; i < 7; ++i)
            for (int j = 0; j < 5; ++j) A[i][j] = W1[i * 5 + j];
        for (int i = 0; i < 7; ++i)
            for (int j = 0; j < 4; ++j) {
                float s = 0.f;
                for (int k = 0; k < 5; ++k) s += A[i][k] * W2[k * 4 + j];
                B[i][j] = s;
            }
        for (int i = 0; i < 7; ++i)
            for (int j = 0; j < 3; ++j) {
                float s = 0.f;
                for (int k = 0; k < 4; ++k) s += B[i][k] * W3[k * 3 + j];
                C[i][j] = s;
            }
        for (int i = 0; i < 7; ++i)
            for (int j = 0; j < 2; ++j) {
                float s = 0.f;
                for (int k = 0; k < 3; ++k) s += C[i][k] * W4[k * 2 + j];
                D[i][j] = s;
            }
        for (int i = 0; i < 7; ++i)
            sw[i] = D[i][0] * W5[0] + D[i][1] * W5[1];

        // bias chain
        float v2[4], v3[3], v4[2];
        for (int j = 0; j < 4; ++j) {
            float s = b2[j];
            for (int k = 0; k < 5; ++k) s += b1[k] * W2[k * 4 + j];
            v2[j] = s;
        }
        for (int j = 0; j < 3; ++j) {
            float s = b3[j];
            for (int k = 0; k < 4; ++k) s += v2[k] * W3[k * 3 + j];
            v3[j] = s;
        }
        for (int j = 0; j < 2; ++j) {
            float s = b4[j];
            for (int k = 0; k < 3; ++k) s += v3[k] * W4[k * 2 + j];
            v4[j] = s;
        }
        sw[7] = v4[0] * W5[0] + v4[1] * W5[1] + b5[0];
    }
    __syncthreads();

    const float w0 = sw[0], w1 = sw[1], w2 = sw[2], w3 = sw[3];
    const float w4 = sw[4], w5 = sw[5], w6 = sw[6], c = sw[7];

    // Each thread handles 4 rows = 28 floats = exactly 7 float4 loads.
    // Output: 4 floats = one coalesced float4 store per thread.
    const float4* __restrict__ X4 = reinterpret_cast<const float4*>(X);
    float4* __restrict__ out4 = reinterpret_cast<float4*>(out);

    const int ngroups = nrows >> 2;
    const int stride = gridDim.x * blockDim.x;

    for (int g = blockIdx.x * blockDim.x + threadIdx.x; g < ngroups; g += stride) {
        float a[28];
        #pragma unroll
        for (int k = 0; k < 7; ++k) {
            float4 f = X4[(size_t)g * 7 + k];
            a[4 * k + 0] = f.x;
            a[4 * k + 1] = f.y;
            a[4 * k + 2] = f.z;
            a[4 * k + 3] = f.w;
        }
        float4 r;
        float* rp = &r.x;
        #pragma unroll
        for (int rr = 0; rr < 4; ++rr) {
            const float* row = &a[rr * 7];
            float s = c + row[0] * w0 + row[1] * w1 + row[2] * w2 + row[3] * w3
                        + row[4] * w4 + row[5] * w5 + row[6] * w6;
            rp[rr] = 1.0f / (1.0f + __expf(-s));
        }
        out4[g] = r;
    }

    // Tail rows (nrows % 4) — unused for 4M rows, kept for generality.
    if (blockIdx.x == 0 && (int)threadIdx.x < (nrows & 3)) {
        int r = (ngroups << 2) + threadIdx.x;
        const float* row = X + (size_t)r * 7;
        float s = c;
        #pragma unroll
        for (int j = 0; j < 7; ++j) s += row[j] * sw[j];
        out[r] = 1.0f / (1.0f + __expf(-s));
    }
}

extern "C" void kernel_launch(void* const* d_in, const int* in_sizes, int n_in,
                              void* d_out, int out_size, void* d_ws, size_t ws_size,
                              hipStream_t stream) {
    const float* X  = (const float*)d_in[0];
    const float* W1 = (const float*)d_in[1];
    const float* b1 = (const float*)d_in[2];
    const float* W2 = (const float*)d_in[3];
    const float* b2 = (const float*)d_in[4];
    const float* W3 = (const float*)d_in[5];
    const float* b3 = (const float*)d_in[6];
    const float* W4 = (const float*)d_in[7];
    const float* b4 = (const float*)d_in[8];
    const float* W5 = (const float*)d_in[9];
    const float* b5 = (const float*)d_in[10];
    float* out = (float*)d_out;

    const int nrows = in_sizes[0] / 7;  // 4,000,000
    const int ngroups = nrows >> 2;     // 1,000,000
    int blocks = (ngroups + 255) / 256;
    if (blocks < 1) blocks = 1;

    SimpleNN2_kernel<<<blocks, 256, 0, stream>>>(
        X, W1, b1, W2, b2, W3, b3, W4, b4, W5, b5, out, nrows);
}